// Round 14
// baseline (346.774 us; speedup 1.0000x reference)
//
#include <hip/hip_runtime.h>
#include <hip/hip_bf16.h>

typedef short short8 __attribute__((ext_vector_type(8)));
typedef float f32x4 __attribute__((ext_vector_type(4)));

#define MFMA32(a, b, c) __builtin_amdgcn_mfma_f32_16x16x32_bf16(a, b, c, 0, 0, 0)

#if __has_builtin(__builtin_amdgcn_exp2f)
#define EXP2F(x) __builtin_amdgcn_exp2f(x)
#else
#define EXP2F(x) exp2f(x)
#endif

// async global->LDS, 16B per lane; LDS dest = wave-uniform base + lane*16
#define GLL16(gp, lp) __builtin_amdgcn_global_load_lds(                                  \
    (__attribute__((address_space(1))) unsigned int*)(unsigned long long)(const void*)(gp), \
    (__attribute__((address_space(3))) unsigned int*)(lp), 16, 0, 0)

// fp32 -> bf16 RNE
__device__ __forceinline__ unsigned short f2b(float f) {
    union { float f; unsigned int u; } v;
    v.f = f;
    unsigned int u = v.u;
    return (unsigned short)((u + 0x7fffu + ((u >> 16) & 1u)) >> 16);
}

// ---------------- merged cvt: x (+mask) and 4 weights ----------------
// maskbuf carries the softmax fixed-max fold: valid key -> -16.0 (global
// fixed max in log2 domain), pad key -> -1e30. exp2(s + mask) needs no
// per-element subtract and no running max; 2^-16 cancels in normalization.
__global__ void cvt_all(const float* __restrict__ x,
                        const float* __restrict__ w0, const float* __restrict__ w1,
                        const float* __restrict__ w2, const float* __restrict__ w3,
                        unsigned short* __restrict__ xb, unsigned short* __restrict__ wb,
                        float* __restrict__ maskbuf) {
    int blk = blockIdx.x;
    if (blk < 4096) {
        int i = blk * 256 + threadIdx.x;           // 0..1048575 float4s
        float4 v = ((const float4*)x)[i];
        ushort4 o;
        o.x = f2b(v.x); o.y = f2b(v.y); o.z = f2b(v.z); o.w = f2b(v.w);
        ((ushort4*)xb)[i] = o;
        if ((i & 255) == 0)
            maskbuf[i >> 8] = (v.x != 0.0f) ? -16.0f : -1e30f;
    } else {
        int wi = blk - 4096;
        int widx = wi >> 10;
        int i = (wi & 1023) * 256 + threadIdx.x;   // 0..262143 float4s
        const float* src = widx == 0 ? w0 : (widx == 1 ? w1 : (widx == 2 ? w2 : w3));
        float4 v = ((const float4*)src)[i];
        ushort4 o;
        o.x = f2b(v.x); o.y = f2b(v.y); o.z = f2b(v.z); o.w = f2b(v.w);
        ((ushort4*)(wb + ((size_t)widx << 20)))[i] = o;
    }
}

// fold softmax scale (Dh^-0.5) and log2(e) into Q so attn uses raw exp2
#define QSCALE (0.125f * 1.44269504088896341f)

// ---------------- fused QKV GEMM: 512 thr / 8 waves, dbuf, 1 barrier/iter ----------------
// 128x128 tiles, grid (24,32) = 768 blocks = 3/CU (__launch_bounds__(512,6),
// 32 KB LDS). T1 bijective XCD-chunk swizzle: XCD k owns virtual x in
// [3k,3k+3) — its 3 B-panels (768 KB) are L2-resident, A-tiles get 3x
// in-XCD reuse (R13: −2.6 µs with proj). Wave grid 2x4, wave tile 64x32.
__global__ __launch_bounds__(512, 6) void gemm_qkv(
        const unsigned short* __restrict__ A,
        const unsigned short* __restrict__ wq, const unsigned short* __restrict__ wk,
        const unsigned short* __restrict__ wv,
        const float* __restrict__ bq, const float* __restrict__ bk,
        const float* __restrict__ bv,
        unsigned short* __restrict__ qbuf, unsigned short* __restrict__ kbuf,
        unsigned short* __restrict__ vbuf) {
    __shared__ __attribute__((aligned(16))) unsigned short As[2][128 * 32];
    __shared__ __attribute__((aligned(16))) unsigned short Bs[2][128 * 32];
    int tid = threadIdx.x;
    int lane = tid & 63, wave = tid >> 6;            // wave 0..7
    int lane15 = lane & 15, quad = lane >> 4;
    // T1 XCD-chunk swizzle: physical id (x fastest) -> virtual x-major tile
    int orig = blockIdx.x + 24 * blockIdx.y;         // 0..767
    int v = (orig & 7) * 96 + (orig >> 3);           // XCD (orig&7) gets 96 consecutive v
    int xx = v >> 5, yy = v & 31;                    // virtual (x 0..23, y 0..31)
    int seg = xx >> 3;
    int bn = (xx & 7) * 128;
    int bm = yy * 128;
    const unsigned short* Bw = seg == 0 ? wq : (seg == 1 ? wk : wv);
    const float* bias = seg == 0 ? bq : (seg == 1 ? bk : bv);
    int wm = (wave >> 2) * 64, wn = (wave & 3) * 32; // wave tile 64x32

    f32x4 acc[4][2];
#pragma unroll
    for (int i = 0; i < 4; i++)
#pragma unroll
        for (int j = 0; j < 2; j++) acc[i][j] = (f32x4){0.f, 0.f, 0.f, 0.f};

    int arow = tid >> 2, acol = (tid & 3) * 8;       // 512 thr cover 128x32 tile
    const unsigned short* A0 = &A[(size_t)(bm + arow) * 1024 + acol];
    const unsigned short* B0 = &Bw[(size_t)(bn + arow) * 1024 + acol];

    // prologue: stage k-tile 0 into buffer 0 (1 A + 1 B chunk per thread)
    GLL16(A0, &As[0][(size_t)tid * 8]);
    GLL16(B0, &Bs[0][(size_t)tid * 8]);

    for (int it = 0; it < 32; it++) {
        int cur = it & 1;
        __syncthreads();                 // tile[cur] ready; prior reads drained
        if (it < 31) {                   // prefetch tile[cur^1]
            int kn = (it + 1) * 32;
            GLL16(A0 + kn, &As[cur ^ 1][(size_t)tid * 8]);
            GLL16(B0 + kn, &Bs[cur ^ 1][(size_t)tid * 8]);
        }
        const unsigned short* as = As[cur];
        const unsigned short* bs = Bs[cur];
        short8 af[4], bf[2];
#pragma unroll
        for (int i = 0; i < 4; i++)
            af[i] = *(const short8*)&as[(wm + i * 16 + lane15) * 32 + quad * 8];
#pragma unroll
        for (int j = 0; j < 2; j++)
            bf[j] = *(const short8*)&bs[(wn + j * 16 + lane15) * 32 + quad * 8];
#pragma unroll
        for (int i = 0; i < 4; i++)
#pragma unroll
            for (int j = 0; j < 2; j++)
                acc[i][j] = MFMA32(af[i], bf[j], acc[i][j]);
    }

    int bb = bm >> 11;
#pragma unroll
    for (int j = 0; j < 2; j++) {
        int nl = bn + wn + j * 16 + lane15;     // 0..1023
        int h = nl >> 6, d = nl & 63;
        float bv_ = bias[nl];
        if (seg == 2) {
            size_t vbase = ((size_t)((bb * 16 + h) * 64 + d)) * 2048;
#pragma unroll
            for (int i = 0; i < 4; i++) {
                int tk0 = (bm & 2047) + wm + i * 16 + quad * 4;
                int grp = tk0 >> 5;
                ushort4 pk;
                pk.x = f2b(acc[i][j][0] + bv_);
                pk.y = f2b(acc[i][j][1] + bv_);
                pk.z = f2b(acc[i][j][2] + bv_);
                pk.w = f2b(acc[i][j][3] + bv_);
                *(ushort4*)&vbuf[vbase + grp * 32 + quad * 8 + (i & 1) * 4] = pk;
            }
        } else {
#pragma unroll
            for (int i = 0; i < 4; i++)
#pragma unroll
                for (int r = 0; r < 4; r++) {
                    int m = bm + wm + i * 16 + quad * 4 + r;
                    int tk = m & 2047;
                    float v2 = acc[i][j][r] + bv_;
                    size_t off = ((size_t)((bb * 16 + h) * 2048 + tk)) * 64 + d;
                    if (seg == 0) qbuf[off] = f2b(v2 * QSCALE);
                    else          kbuf[off] = f2b(v2);
                }
        }
    }
}

// ---------------- output projection GEMM: 64x64 tiles, BK=64, 4 blocks/CU ----------------
// BK=64: 8 MFMA + 8 ds_read + 4 GLL per wave-iter, 16 iters. LDS 32 KB keeps
// 4 blocks/CU. XOR chunk swizzle on 128B LDS rows (0 conflicts measured).
// T1 bijective XCD-chunk swizzle: XCD k owns virtual bx in [2k,2k+2).
__global__ __launch_bounds__(256, 4) void gemm_proj(
        const unsigned short* __restrict__ A, const unsigned short* __restrict__ Bw,
        const float* __restrict__ bias, float* __restrict__ out) {
    __shared__ __attribute__((aligned(16))) unsigned short As[2][64 * 64];
    __shared__ __attribute__((aligned(16))) unsigned short Bs[2][64 * 64];
    int tid = threadIdx.x;
    int lane = tid & 63, wave = tid >> 6;            // wave 0..3
    int lane15 = lane & 15, quad = lane >> 4;
    int x7 = lane15 & 7;
    // T1 XCD-chunk swizzle: physical (x fastest) -> virtual x-major
    int orig = blockIdx.x + 16 * blockIdx.y;         // 0..1023
    int v = (orig & 7) * 128 + (orig >> 3);
    int bxv = v >> 6, byv = v & 63;                  // virtual (bx 0..15, by 0..63)
    int bn = bxv * 64, bm = byv * 64;
    int wm = (wave >> 1) * 32, wn = (wave & 1) * 32; // wave tile 32x32

    f32x4 acc[2][2];
#pragma unroll
    for (int i = 0; i < 2; i++)
#pragma unroll
        for (int j = 0; j < 2; j++) acc[i][j] = (f32x4){0.f, 0.f, 0.f, 0.f};

    // staging: per iter, A tile 64x64 (512 chunks) + B tile 64x64 (512 chunks);
    // each of 256 threads does 2 A + 2 B GLLs. Chunk ci: row=ci>>3, slot=ci&7
    // holds global k-chunk (ci&7)^(row&7).
#define PSTAGE(buf, kt)                                                                \
    _Pragma("unroll")                                                                  \
    for (int r2 = 0; r2 < 2; r2++) {                                                   \
        int ci = tid + r2 * 256;                                                       \
        int rr = ci >> 3, cc = (ci & 7) ^ (rr & 7);                                    \
        GLL16(&A[(size_t)(bm + rr) * 1024 + (kt) * 64 + cc * 8], &As[buf][(size_t)ci * 8]); \
        GLL16(&Bw[(size_t)(bn + rr) * 1024 + (kt) * 64 + cc * 8], &Bs[buf][(size_t)ci * 8]); \
    }

    PSTAGE(0, 0);

    for (int it = 0; it < 16; it++) {
        int cur = it & 1;
        __syncthreads();
        if (it < 15) PSTAGE(cur ^ 1, it + 1);
        const unsigned short* as = As[cur];
        const unsigned short* bs = Bs[cur];
#pragma unroll
        for (int ksub = 0; ksub < 2; ksub++) {
            short8 af[2], bf[2];
#pragma unroll
            for (int i = 0; i < 2; i++)
                af[i] = *(const short8*)&as[(wm + i * 16 + lane15) * 64 + (((ksub * 4 + quad) ^ x7)) * 8];
#pragma unroll
            for (int j = 0; j < 2; j++)
                bf[j] = *(const short8*)&bs[(wn + j * 16 + lane15) * 64 + (((ksub * 4 + quad) ^ x7)) * 8];
#pragma unroll
            for (int i = 0; i < 2; i++)
#pragma unroll
                for (int j = 0; j < 2; j++)
                    acc[i][j] = MFMA32(af[i], bf[j], acc[i][j]);
        }
    }

#pragma unroll
    for (int j = 0; j < 2; j++) {
        int n = bn + wn + j * 16 + lane15;
        float bv_ = bias[n];
#pragma unroll
        for (int i = 0; i < 2; i++)
#pragma unroll
            for (int r = 0; r < 4; r++) {
                int m = bm + wm + i * 16 + quad * 4 + r;
                out[(size_t)m * 1024 + n] = acc[i][j][r] + bv_;
            }
    }
}

// ---------------- flash attention v13: 3 blocks/CU via single-buffered V ----------------
// R14: same split-K two-team structure (512 blocks x 512 thr, 2 teams of
// 4 waves x 32q, KVBLK=64, fixed-max softmax, mask in C-init, setprio) but
// LDS 67.5 -> 50 KB: K double-buffered (2x8KB/team), V SINGLE-buffered
// (8KB/team) => 3 blocks/CU resident (150 <= 160 KB), 24 waves/CU = 6/SIMD
// (was 4). Register state unchanged (60 VGPR, cap 85 at (512,6): no spill
// possible by construction — the R9 lesson). Cost: 2 barriers/iter — V[it]
// staged at top of iter, drained by the pre-PV barrier; its latency hides
// under QK+softmax (~2000 cyc vs ~500 L2). K-prefetch window shrinks to the
// QK+softmax phase (still ample). Same trade that won R2: more independent
// barrier groups at higher wave count beats fewer barriers at lower.
__global__ __launch_bounds__(512, 6) void attn_kernel(
        const unsigned short* __restrict__ qbuf, const unsigned short* __restrict__ kbuf,
        const unsigned short* __restrict__ vtbuf, const float* __restrict__ maskbuf,
        unsigned short* __restrict__ attnout) {
    __shared__ __attribute__((aligned(16))) unsigned short Ks[2][2][64 * 64];  // 32 KB
    __shared__ __attribute__((aligned(16))) unsigned short Vs[2][64 * 64];     // 16 KB
    __shared__ float Lm[4][2][64];                                             // 2 KB

    int id = blockIdx.x;
    int combo = (id & 7) | (((id >> 7) & 3) << 3);   // same (b,h) stays on one XCD
    int qt = (id >> 3) & 15;
    int b = combo >> 4, h = combo & 15;
    int tid = threadIdx.x, lane = tid & 63, wave = tid >> 6;   // wave 0..7
    int team = wave >> 2, wp = wave & 3;
    int lane15 = lane & 15, quad = lane >> 4;
    int q0 = qt * 128 + wp * 32;

    const unsigned short* Q  = qbuf  + (size_t)combo * 2048 * 64;
    const unsigned short* Kp = kbuf  + (size_t)combo * 2048 * 64 + (size_t)team * 1024 * 64;
    const unsigned short* Vt = vtbuf + (size_t)combo * 64 * 2048 + team * 1024;
    const float* mb = maskbuf + b * 2048 + team * 1024;

    // Q as 16x16x32 B-operand: B[n=lane15][k=quad*8+j]; two 16-q tiles, two k-halves
    short8 qf[2][2];
#pragma unroll
    for (int a = 0; a < 2; a++)
#pragma unroll
        for (int g = 0; g < 2; g++)
            qf[a][g] = *(const short8*)&Q[(size_t)(q0 + a * 16 + lane15) * 64 + g * 32 + quad * 8];

    float l_run[2] = {0.f, 0.f};
    f32x4 o[2][4];
#pragma unroll
    for (int a = 0; a < 2; a++)
#pragma unroll
        for (int c = 0; c < 4; c++) o[a][c] = (f32x4){0.f, 0.f, 0.f, 0.f};

    int x7 = lane15 & 7;
    int ci0 = tid & 255;            // per-team chunk id 0..255 (wave-contiguous)

    // per team-iter: K tile 64x64 (512 chunks, dbuf) + V tile 64x64 (512
    // chunks, single buffer); each of the 256 team-threads does 2+2 GLLs.
#define STAGE_K(buf, kt)                                                               \
    _Pragma("unroll")                                                                  \
    for (int r2 = 0; r2 < 2; r2++) {                                                   \
        int ci = ci0 + r2 * 256;                                                       \
        int rr = ci >> 3, cc = (ci & 7) ^ (rr & 7);                                    \
        GLL16(&Kp[(size_t)((kt) * 64 + rr) * 64 + cc * 8], &Ks[team][buf][(size_t)ci * 8]); \
    }
#define STAGE_V(kt)                                                                    \
    _Pragma("unroll")                                                                  \
    for (int r2 = 0; r2 < 2; r2++) {                                                   \
        int ci = ci0 + r2 * 256;                                                       \
        int rr = ci >> 3, cc = (ci & 7) ^ (rr & 7);                                    \
        GLL16(&Vt[(size_t)rr * 2048 + (kt) * 64 + cc * 8], &Vs[team][(size_t)ci * 8]); \
    }

    STAGE_K(0, 0);

    for (int it = 0; it < 16; it++) {
        int cur = it & 1;
        int kb = it * 64;
        __syncthreads();                       // K[cur] ready; V buffer free
        if (it < 15) STAGE_K(cur ^ 1, it + 1);
        STAGE_V(it);

        const unsigned short* ks = Ks[team][cur];

        // ---- S^T = K.Q^T : 4 key-tiles x 2 q-tiles, mask in C-init ----
        f32x4 s[2][4];
        __builtin_amdgcn_s_setprio(1);
#pragma unroll
        for (int t = 0; t < 4; t++) {
            f32x4 mkt = *(const f32x4*)&mb[kb + t * 16 + quad * 4];
            int row = t * 16 + lane15;
            short8 k0 = *(const short8*)&ks[row * 64 + (quad ^ x7) * 8];
            short8 k1 = *(const short8*)&ks[row * 64 + ((quad + 4) ^ x7) * 8];
            f32x4 t0 = MFMA32(k0, qf[0][0], mkt);
            s[0][t] = MFMA32(k1, qf[0][1], t0);
            f32x4 t1 = MFMA32(k0, qf[1][0], mkt);
            s[1][t] = MFMA32(k1, qf[1][1], t1);
        }
        __builtin_amdgcn_s_setprio(0);

        // ---- fixed-max softmax: exp2 directly + pack P into MFMA32 B-frags ----
        short8 pb8[2][2];
#pragma unroll
        for (int a = 0; a < 2; a++) {
            float ls = 0.f;
#pragma unroll
            for (int g = 0; g < 2; g++) {
                float e0 = EXP2F(s[a][2 * g][0]);
                float e1 = EXP2F(s[a][2 * g][1]);
                float e2 = EXP2F(s[a][2 * g][2]);
                float e3 = EXP2F(s[a][2 * g][3]);
                float f0 = EXP2F(s[a][2 * g + 1][0]);
                float f1 = EXP2F(s[a][2 * g + 1][1]);
                float f2 = EXP2F(s[a][2 * g + 1][2]);
                float f3 = EXP2F(s[a][2 * g + 1][3]);
                ls += ((e0 + e1) + (e2 + e3)) + ((f0 + f1) + (f2 + f3));
                union { uint4 u; short8 sv; } pu;   // bf16 truncation pack (P >= 0)
                pu.u.x = __builtin_amdgcn_perm(__float_as_uint(e1), __float_as_uint(e0), 0x07060302u);
                pu.u.y = __builtin_amdgcn_perm(__float_as_uint(e3), __float_as_uint(e2), 0x07060302u);
                pu.u.z = __builtin_amdgcn_perm(__float_as_uint(f1), __float_as_uint(f0), 0x07060302u);
                pu.u.w = __builtin_amdgcn_perm(__float_as_uint(f3), __float_as_uint(f2), 0x07060302u);
                pb8[a][g] = pu.sv;
            }
            l_run[a] += ls;
        }

        __syncthreads();                       // V[it] ready (drains staging)
        const unsigned short* vs = Vs[team];

        // ---- O^T += V^T.P^T : MFMA32, A-frag = one b128, shared by both q-tiles ----
        __builtin_amdgcn_s_setprio(1);
#pragma unroll
        for (int c = 0; c < 4; c++) {
            int d = c * 16 + lane15;
#pragma unroll
            for (int g = 0; g < 2; g++) {
                int skc = (g * 4 + quad) ^ x7;
                short8 vv = *(const short8*)&vs[d * 64 + skc * 8];
                o[0][c] = MFMA32(vv, pb8[0][g], o[0][c]);
                o[1][c] = MFMA32(vv, pb8[1][g], o[1][c]);
            }
        }
        __builtin_amdgcn_s_setprio(0);
    }

    // ---- split-K merge: team1 -> LDS (dead K-staging region), team0 adds ----
    __syncthreads();
    f32x4* omv = (f32x4*)&Ks[0][0][0];           // 2048 f32x4 = 32 KB (Ks region)
    if (team == 1) {
#pragma unroll
        for (int a = 0; a < 2; a++) {
#pragma unroll
            for (int c = 0; c < 4; c++)
                omv[(wp * 8 + a * 4 + c) * 64 + lane] = o[a][c];
            Lm[wp][a][lane] = l_run[a];
        }
    }
    __syncthreads();
    if (team == 0) {
#pragma unroll
        for (int a = 0; a < 2; a++) {
            l_run[a] += Lm[wp][a][lane];
#pragma unroll
            for (int c = 0; c < 4; c++)
                o[a][c] += omv[(wp * 8 + a * 4 + c) * 64 + lane];
        }
        // ---- epilogue (fixed-max: partials sum exactly; 2^-16 cancels in 1/l) ----
#pragma unroll
        for (int a = 0; a < 2; a++) {
            float l = l_run[a];
            l += __shfl_xor(l, 16);
            l += __shfl_xor(l, 32);
            float rl = 1.0f / l;
            size_t row = (size_t)(b * 2048 + q0 + a * 16 + lane15) * 1024 + h * 64 + quad * 4;
#pragma unroll
            for (int c = 0; c < 4; c++) {
                ushort4 pk;
                pk.x = f2b(o[a][c][0] * rl);
                pk.y = f2b(o[a][c][1] * rl);
                pk.z = f2b(o[a][c][2] * rl);
                pk.w = f2b(o[a][c][3] * rl);
                *(ushort4*)&attnout[row + c * 16] = pk;
            }
        }
    }
}

extern "C" void kernel_launch(void* const* d_in, const int* in_sizes, int n_in,
                              void* d_out, int out_size, void* d_ws, size_t ws_size,
                              hipStream_t stream) {
    const float* x    = (const float*)d_in[0];
    const float* wq_w = (const float*)d_in[1];
    const float* wq_b = (const float*)d_in[2];
    const float* wk_w = (const float*)d_in[3];
    const float* wk_b = (const float*)d_in[4];
    const float* wv_w = (const float*)d_in[5];
    const float* wv_b = (const float*)d_in[6];
    const float* wo_w = (const float*)d_in[7];
    const float* wo_b = (const float*)d_in[8];
    float* out = (float*)d_out;

    char* ws = (char*)d_ws;
    size_t off = 0;
    unsigned short* xb      = (unsigned short*)(ws + off); off += (size_t)4096 * 1024 * 2;
    unsigned short* wb      = (unsigned short*)(ws + off); off += (size_t)4 * 1024 * 1024 * 2;
    unsigned short* qbuf    = (unsigned short*)(ws + off); off += (size_t)4096 * 1024 * 2;
    unsigned short* kbuf    = (unsigned short*)(ws + off); off += (size_t)4096 * 1024 * 2;
    unsigned short* vbuf    = (unsigned short*)(ws + off); off += (size_t)4096 * 1024 * 2;
    unsigned short* attnout = (unsigned short*)(ws + off); off += (size_t)4096 * 1024 * 2;
    float* maskbuf          = (float*)(ws + off);          off += 4096 * 4;

    unsigned short* wqb = wb;
    unsigned short* wkb = wb + (1u << 20);
    unsigned short* wvb = wb + (2u << 20);
    unsigned short* wob = wb + (3u << 20);

    cvt_all<<<8192, 256, 0, stream>>>(x, wq_w, wk_w, wv_w, wo_w, xb, wb, maskbuf);

    gemm_qkv<<<dim3(24, 32), 512, 0, stream>>>(xb, wqb, wkb, wvb,
                                               wq_b, wk_b, wv_b, qbuf, kbuf, vbuf);

    attn_kernel<<<512, 512, 0, stream>>>(qbuf, kbuf, vbuf, maskbuf, attnout);

    gemm_proj<<<dim3(16, 64), 256, 0, stream>>>(attnout, wob, wo_b, out);
}

// Round 15
// 185.397 us; speedup vs baseline: 1.8704x; 1.8704x over previous
//
#include <hip/hip_runtime.h>
#include <hip/hip_bf16.h>

typedef short short8 __attribute__((ext_vector_type(8)));
typedef float f32x4 __attribute__((ext_vector_type(4)));

#define MFMA32(a, b, c) __builtin_amdgcn_mfma_f32_16x16x32_bf16(a, b, c, 0, 0, 0)

#if __has_builtin(__builtin_amdgcn_exp2f)
#define EXP2F(x) __builtin_amdgcn_exp2f(x)
#else
#define EXP2F(x) exp2f(x)
#endif

// async global->LDS, 16B per lane; LDS dest = wave-uniform base + lane*16
#define GLL16(gp, lp) __builtin_amdgcn_global_load_lds(                                  \
    (__attribute__((address_space(1))) unsigned int*)(unsigned long long)(const void*)(gp), \
    (__attribute__((address_space(3))) unsigned int*)(lp), 16, 0, 0)

// fp32 -> bf16 RNE
__device__ __forceinline__ unsigned short f2b(float f) {
    union { float f; unsigned int u; } v;
    v.f = f;
    unsigned int u = v.u;
    return (unsigned short)((u + 0x7fffu + ((u >> 16) & 1u)) >> 16);
}

// ---------------- merged cvt: x (+mask) and 4 weights ----------------
// maskbuf carries the softmax fixed-max fold: valid key -> -16.0 (global
// fixed max in log2 domain), pad key -> -1e30. exp2(s + mask) needs no
// per-element subtract and no running max; 2^-16 cancels in normalization.
__global__ void cvt_all(const float* __restrict__ x,
                        const float* __restrict__ w0, const float* __restrict__ w1,
                        const float* __restrict__ w2, const float* __restrict__ w3,
                        unsigned short* __restrict__ xb, unsigned short* __restrict__ wb,
                        float* __restrict__ maskbuf) {
    int blk = blockIdx.x;
    if (blk < 4096) {
        int i = blk * 256 + threadIdx.x;           // 0..1048575 float4s
        float4 v = ((const float4*)x)[i];
        ushort4 o;
        o.x = f2b(v.x); o.y = f2b(v.y); o.z = f2b(v.z); o.w = f2b(v.w);
        ((ushort4*)xb)[i] = o;
        if ((i & 255) == 0)
            maskbuf[i >> 8] = (v.x != 0.0f) ? -16.0f : -1e30f;
    } else {
        int wi = blk - 4096;
        int widx = wi >> 10;
        int i = (wi & 1023) * 256 + threadIdx.x;   // 0..262143 float4s
        const float* src = widx == 0 ? w0 : (widx == 1 ? w1 : (widx == 2 ? w2 : w3));
        float4 v = ((const float4*)src)[i];
        ushort4 o;
        o.x = f2b(v.x); o.y = f2b(v.y); o.z = f2b(v.z); o.w = f2b(v.w);
        ((ushort4*)(wb + ((size_t)widx << 20)))[i] = o;
    }
}

// fold softmax scale (Dh^-0.5) and log2(e) into Q so attn uses raw exp2
#define QSCALE (0.125f * 1.44269504088896341f)

// ---------------- fused QKV GEMM: 512 thr / 8 waves, dbuf, 1 barrier/iter ----------------
// 128x128 tiles, grid (24,32) = 768 blocks = 3/CU (__launch_bounds__(512,6),
// 32 KB LDS). T1 bijective XCD-chunk swizzle: XCD k owns virtual x in
// [3k,3k+3) — its 3 B-panels (768 KB) are L2-resident, A-tiles get 3x
// in-XCD reuse (R13: −2.6 µs with proj). Wave grid 2x4, wave tile 64x32.
__global__ __launch_bounds__(512, 6) void gemm_qkv(
        const unsigned short* __restrict__ A,
        const unsigned short* __restrict__ wq, const unsigned short* __restrict__ wk,
        const unsigned short* __restrict__ wv,
        const float* __restrict__ bq, const float* __restrict__ bk,
        const float* __restrict__ bv,
        unsigned short* __restrict__ qbuf, unsigned short* __restrict__ kbuf,
        unsigned short* __restrict__ vbuf) {
    __shared__ __attribute__((aligned(16))) unsigned short As[2][128 * 32];
    __shared__ __attribute__((aligned(16))) unsigned short Bs[2][128 * 32];
    int tid = threadIdx.x;
    int lane = tid & 63, wave = tid >> 6;            // wave 0..7
    int lane15 = lane & 15, quad = lane >> 4;
    // T1 XCD-chunk swizzle: physical id (x fastest) -> virtual x-major tile
    int orig = blockIdx.x + 24 * blockIdx.y;         // 0..767
    int v = (orig & 7) * 96 + (orig >> 3);           // XCD (orig&7) gets 96 consecutive v
    int xx = v >> 5, yy = v & 31;                    // virtual (x 0..23, y 0..31)
    int seg = xx >> 3;
    int bn = (xx & 7) * 128;
    int bm = yy * 128;
    const unsigned short* Bw = seg == 0 ? wq : (seg == 1 ? wk : wv);
    const float* bias = seg == 0 ? bq : (seg == 1 ? bk : bv);
    int wm = (wave >> 2) * 64, wn = (wave & 3) * 32; // wave tile 64x32

    f32x4 acc[4][2];
#pragma unroll
    for (int i = 0; i < 4; i++)
#pragma unroll
        for (int j = 0; j < 2; j++) acc[i][j] = (f32x4){0.f, 0.f, 0.f, 0.f};

    int arow = tid >> 2, acol = (tid & 3) * 8;       // 512 thr cover 128x32 tile
    const unsigned short* A0 = &A[(size_t)(bm + arow) * 1024 + acol];
    const unsigned short* B0 = &Bw[(size_t)(bn + arow) * 1024 + acol];

    // prologue: stage k-tile 0 into buffer 0 (1 A + 1 B chunk per thread)
    GLL16(A0, &As[0][(size_t)tid * 8]);
    GLL16(B0, &Bs[0][(size_t)tid * 8]);

    for (int it = 0; it < 32; it++) {
        int cur = it & 1;
        __syncthreads();                 // tile[cur] ready; prior reads drained
        if (it < 31) {                   // prefetch tile[cur^1]
            int kn = (it + 1) * 32;
            GLL16(A0 + kn, &As[cur ^ 1][(size_t)tid * 8]);
            GLL16(B0 + kn, &Bs[cur ^ 1][(size_t)tid * 8]);
        }
        const unsigned short* as = As[cur];
        const unsigned short* bs = Bs[cur];
        short8 af[4], bf[2];
#pragma unroll
        for (int i = 0; i < 4; i++)
            af[i] = *(const short8*)&as[(wm + i * 16 + lane15) * 32 + quad * 8];
#pragma unroll
        for (int j = 0; j < 2; j++)
            bf[j] = *(const short8*)&bs[(wn + j * 16 + lane15) * 32 + quad * 8];
#pragma unroll
        for (int i = 0; i < 4; i++)
#pragma unroll
            for (int j = 0; j < 2; j++)
                acc[i][j] = MFMA32(af[i], bf[j], acc[i][j]);
    }

    int bb = bm >> 11;
#pragma unroll
    for (int j = 0; j < 2; j++) {
        int nl = bn + wn + j * 16 + lane15;     // 0..1023
        int h = nl >> 6, d = nl & 63;
        float bv_ = bias[nl];
        if (seg == 2) {
            size_t vbase = ((size_t)((bb * 16 + h) * 64 + d)) * 2048;
#pragma unroll
            for (int i = 0; i < 4; i++) {
                int tk0 = (bm & 2047) + wm + i * 16 + quad * 4;
                int grp = tk0 >> 5;
                ushort4 pk;
                pk.x = f2b(acc[i][j][0] + bv_);
                pk.y = f2b(acc[i][j][1] + bv_);
                pk.z = f2b(acc[i][j][2] + bv_);
                pk.w = f2b(acc[i][j][3] + bv_);
                *(ushort4*)&vbuf[vbase + grp * 32 + quad * 8 + (i & 1) * 4] = pk;
            }
        } else {
#pragma unroll
            for (int i = 0; i < 4; i++)
#pragma unroll
                for (int r = 0; r < 4; r++) {
                    int m = bm + wm + i * 16 + quad * 4 + r;
                    int tk = m & 2047;
                    float v2 = acc[i][j][r] + bv_;
                    size_t off = ((size_t)((bb * 16 + h) * 2048 + tk)) * 64 + d;
                    if (seg == 0) qbuf[off] = f2b(v2 * QSCALE);
                    else          kbuf[off] = f2b(v2);
                }
        }
    }
}

// ---------------- output projection GEMM: 64x64 tiles, BK=64, 4 blocks/CU ----------------
// BK=64: 8 MFMA + 8 ds_read + 4 GLL per wave-iter, 16 iters. LDS 32 KB keeps
// 4 blocks/CU. XOR chunk swizzle on 128B LDS rows (0 conflicts measured).
// T1 bijective XCD-chunk swizzle: XCD k owns virtual bx in [2k,2k+2).
__global__ __launch_bounds__(256, 4) void gemm_proj(
        const unsigned short* __restrict__ A, const unsigned short* __restrict__ Bw,
        const float* __restrict__ bias, float* __restrict__ out) {
    __shared__ __attribute__((aligned(16))) unsigned short As[2][64 * 64];
    __shared__ __attribute__((aligned(16))) unsigned short Bs[2][64 * 64];
    int tid = threadIdx.x;
    int lane = tid & 63, wave = tid >> 6;            // wave 0..3
    int lane15 = lane & 15, quad = lane >> 4;
    int x7 = lane15 & 7;
    // T1 XCD-chunk swizzle: physical (x fastest) -> virtual x-major
    int orig = blockIdx.x + 16 * blockIdx.y;         // 0..1023
    int v = (orig & 7) * 128 + (orig >> 3);
    int bxv = v >> 6, byv = v & 63;                  // virtual (bx 0..15, by 0..63)
    int bn = bxv * 64, bm = byv * 64;
    int wm = (wave >> 1) * 32, wn = (wave & 1) * 32; // wave tile 32x32

    f32x4 acc[2][2];
#pragma unroll
    for (int i = 0; i < 2; i++)
#pragma unroll
        for (int j = 0; j < 2; j++) acc[i][j] = (f32x4){0.f, 0.f, 0.f, 0.f};

    // staging: per iter, A tile 64x64 (512 chunks) + B tile 64x64 (512 chunks);
    // each of 256 threads does 2 A + 2 B GLLs. Chunk ci: row=ci>>3, slot=ci&7
    // holds global k-chunk (ci&7)^(row&7).
#define PSTAGE(buf, kt)                                                                \
    _Pragma("unroll")                                                                  \
    for (int r2 = 0; r2 < 2; r2++) {                                                   \
        int ci = tid + r2 * 256;                                                       \
        int rr = ci >> 3, cc = (ci & 7) ^ (rr & 7);                                    \
        GLL16(&A[(size_t)(bm + rr) * 1024 + (kt) * 64 + cc * 8], &As[buf][(size_t)ci * 8]); \
        GLL16(&Bw[(size_t)(bn + rr) * 1024 + (kt) * 64 + cc * 8], &Bs[buf][(size_t)ci * 8]); \
    }

    PSTAGE(0, 0);

    for (int it = 0; it < 16; it++) {
        int cur = it & 1;
        __syncthreads();
        if (it < 15) PSTAGE(cur ^ 1, it + 1);
        const unsigned short* as = As[cur];
        const unsigned short* bs = Bs[cur];
#pragma unroll
        for (int ksub = 0; ksub < 2; ksub++) {
            short8 af[2], bf[2];
#pragma unroll
            for (int i = 0; i < 2; i++)
                af[i] = *(const short8*)&as[(wm + i * 16 + lane15) * 64 + (((ksub * 4 + quad) ^ x7)) * 8];
#pragma unroll
            for (int j = 0; j < 2; j++)
                bf[j] = *(const short8*)&bs[(wn + j * 16 + lane15) * 64 + (((ksub * 4 + quad) ^ x7)) * 8];
#pragma unroll
            for (int i = 0; i < 2; i++)
#pragma unroll
                for (int j = 0; j < 2; j++)
                    acc[i][j] = MFMA32(af[i], bf[j], acc[i][j]);
        }
    }

#pragma unroll
    for (int j = 0; j < 2; j++) {
        int n = bn + wn + j * 16 + lane15;
        float bv_ = bias[n];
#pragma unroll
        for (int i = 0; i < 2; i++)
#pragma unroll
            for (int r = 0; r < 4; r++) {
                int m = bm + wm + i * 16 + quad * 4 + r;
                out[(size_t)m * 1024 + n] = acc[i][j][r] + bv_;
            }
    }
}

// ---------------- flash attention v14: 50 KB LDS, natural (512,4) bounds ----------------
// R15: R14's LDS diet (K dbuf 32 KB + V single-buf 16 KB + Lm 2 KB = 50 KB)
// with the ONE-token fix: __launch_bounds__(512, 4) — the verified bound
// (60 VGPR, no spill for 5 rounds). R14's spill was caused by the (512,6)
// cap, not the LDS diet: at 60 VGPR the per-SIMD pool allows 8 waves/SIMD,
// so VGPR was never the limiter — LDS is. 50 KB -> min(LDS:3, VGPR:4) =
// 3 blocks/CU = 24 waves/CU = 6 waves/SIMD (was 4). Cost: 2 barriers/iter;
// V[it] staged at iter-top, drained by the pre-PV barrier, latency hidden
// under QK+softmax (~2000 cyc vs ~500 L2). Same trade that won R2.
__global__ __launch_bounds__(512, 4) void attn_kernel(
        const unsigned short* __restrict__ qbuf, const unsigned short* __restrict__ kbuf,
        const unsigned short* __restrict__ vtbuf, const float* __restrict__ maskbuf,
        unsigned short* __restrict__ attnout) {
    __shared__ __attribute__((aligned(16))) unsigned short Ks[2][2][64 * 64];  // 32 KB
    __shared__ __attribute__((aligned(16))) unsigned short Vs[2][64 * 64];     // 16 KB
    __shared__ float Lm[4][2][64];                                             // 2 KB

    int id = blockIdx.x;
    int combo = (id & 7) | (((id >> 7) & 3) << 3);   // same (b,h) stays on one XCD
    int qt = (id >> 3) & 15;
    int b = combo >> 4, h = combo & 15;
    int tid = threadIdx.x, lane = tid & 63, wave = tid >> 6;   // wave 0..7
    int team = wave >> 2, wp = wave & 3;
    int lane15 = lane & 15, quad = lane >> 4;
    int q0 = qt * 128 + wp * 32;

    const unsigned short* Q  = qbuf  + (size_t)combo * 2048 * 64;
    const unsigned short* Kp = kbuf  + (size_t)combo * 2048 * 64 + (size_t)team * 1024 * 64;
    const unsigned short* Vt = vtbuf + (size_t)combo * 64 * 2048 + team * 1024;
    const float* mb = maskbuf + b * 2048 + team * 1024;

    // Q as 16x16x32 B-operand: B[n=lane15][k=quad*8+j]; two 16-q tiles, two k-halves
    short8 qf[2][2];
#pragma unroll
    for (int a = 0; a < 2; a++)
#pragma unroll
        for (int g = 0; g < 2; g++)
            qf[a][g] = *(const short8*)&Q[(size_t)(q0 + a * 16 + lane15) * 64 + g * 32 + quad * 8];

    float l_run[2] = {0.f, 0.f};
    f32x4 o[2][4];
#pragma unroll
    for (int a = 0; a < 2; a++)
#pragma unroll
        for (int c = 0; c < 4; c++) o[a][c] = (f32x4){0.f, 0.f, 0.f, 0.f};

    int x7 = lane15 & 7;
    int ci0 = tid & 255;            // per-team chunk id 0..255 (wave-contiguous)

    // per team-iter: K tile 64x64 (512 chunks, dbuf) + V tile 64x64 (512
    // chunks, single buffer); each of the 256 team-threads does 2+2 GLLs.
#define STAGE_K(buf, kt)                                                               \
    _Pragma("unroll")                                                                  \
    for (int r2 = 0; r2 < 2; r2++) {                                                   \
        int ci = ci0 + r2 * 256;                                                       \
        int rr = ci >> 3, cc = (ci & 7) ^ (rr & 7);                                    \
        GLL16(&Kp[(size_t)((kt) * 64 + rr) * 64 + cc * 8], &Ks[team][buf][(size_t)ci * 8]); \
    }
#define STAGE_V(kt)                                                                    \
    _Pragma("unroll")                                                                  \
    for (int r2 = 0; r2 < 2; r2++) {                                                   \
        int ci = ci0 + r2 * 256;                                                       \
        int rr = ci >> 3, cc = (ci & 7) ^ (rr & 7);                                    \
        GLL16(&Vt[(size_t)rr * 2048 + (kt) * 64 + cc * 8], &Vs[team][(size_t)ci * 8]); \
    }

    STAGE_K(0, 0);

    for (int it = 0; it < 16; it++) {
        int cur = it & 1;
        int kb = it * 64;
        __syncthreads();                       // K[cur] ready; V buffer free
        if (it < 15) STAGE_K(cur ^ 1, it + 1);
        STAGE_V(it);

        const unsigned short* ks = Ks[team][cur];

        // ---- S^T = K.Q^T : 4 key-tiles x 2 q-tiles, mask in C-init ----
        f32x4 s[2][4];
        __builtin_amdgcn_s_setprio(1);
#pragma unroll
        for (int t = 0; t < 4; t++) {
            f32x4 mkt = *(const f32x4*)&mb[kb + t * 16 + quad * 4];
            int row = t * 16 + lane15;
            short8 k0 = *(const short8*)&ks[row * 64 + (quad ^ x7) * 8];
            short8 k1 = *(const short8*)&ks[row * 64 + ((quad + 4) ^ x7) * 8];
            f32x4 t0 = MFMA32(k0, qf[0][0], mkt);
            s[0][t] = MFMA32(k1, qf[0][1], t0);
            f32x4 t1 = MFMA32(k0, qf[1][0], mkt);
            s[1][t] = MFMA32(k1, qf[1][1], t1);
        }
        __builtin_amdgcn_s_setprio(0);

        // ---- fixed-max softmax: exp2 directly + pack P into MFMA32 B-frags ----
        short8 pb8[2][2];
#pragma unroll
        for (int a = 0; a < 2; a++) {
            float ls = 0.f;
#pragma unroll
            for (int g = 0; g < 2; g++) {
                float e0 = EXP2F(s[a][2 * g][0]);
                float e1 = EXP2F(s[a][2 * g][1]);
                float e2 = EXP2F(s[a][2 * g][2]);
                float e3 = EXP2F(s[a][2 * g][3]);
                float f0 = EXP2F(s[a][2 * g + 1][0]);
                float f1 = EXP2F(s[a][2 * g + 1][1]);
                float f2 = EXP2F(s[a][2 * g + 1][2]);
                float f3 = EXP2F(s[a][2 * g + 1][3]);
                ls += ((e0 + e1) + (e2 + e3)) + ((f0 + f1) + (f2 + f3));
                union { uint4 u; short8 sv; } pu;   // bf16 truncation pack (P >= 0)
                pu.u.x = __builtin_amdgcn_perm(__float_as_uint(e1), __float_as_uint(e0), 0x07060302u);
                pu.u.y = __builtin_amdgcn_perm(__float_as_uint(e3), __float_as_uint(e2), 0x07060302u);
                pu.u.z = __builtin_amdgcn_perm(__float_as_uint(f1), __float_as_uint(f0), 0x07060302u);
                pu.u.w = __builtin_amdgcn_perm(__float_as_uint(f3), __float_as_uint(f2), 0x07060302u);
                pb8[a][g] = pu.sv;
            }
            l_run[a] += ls;
        }

        __syncthreads();                       // V[it] ready (drains staging)
        const unsigned short* vs = Vs[team];

        // ---- O^T += V^T.P^T : MFMA32, A-frag = one b128, shared by both q-tiles ----
        __builtin_amdgcn_s_setprio(1);
#pragma unroll
        for (int c = 0; c < 4; c++) {
            int d = c * 16 + lane15;
#pragma unroll
            for (int g = 0; g < 2; g++) {
                int skc = (g * 4 + quad) ^ x7;
                short8 vv = *(const short8*)&vs[d * 64 + skc * 8];
                o[0][c] = MFMA32(vv, pb8[0][g], o[0][c]);
                o[1][c] = MFMA32(vv, pb8[1][g], o[1][c]);
            }
        }
        __builtin_amdgcn_s_setprio(0);
    }

    // ---- split-K merge: team1 -> LDS (dead K-staging region), team0 adds ----
    __syncthreads();
    f32x4* omv = (f32x4*)&Ks[0][0][0];           // 2048 f32x4 = 32 KB (Ks region)
    if (team == 1) {
#pragma unroll
        for (int a = 0; a < 2; a++) {
#pragma unroll
            for (int c = 0; c < 4; c++)
                omv[(wp * 8 + a * 4 + c) * 64 + lane] = o[a][c];
            Lm[wp][a][lane] = l_run[a];
        }
    }
    __syncthreads();
    if (team == 0) {
#pragma unroll
        for (int a = 0; a < 2; a++) {
            l_run[a] += Lm[wp][a][lane];
#pragma unroll
            for (int c = 0; c < 4; c++)
                o[a][c] += omv[(wp * 8 + a * 4 + c) * 64 + lane];
        }
        // ---- epilogue (fixed-max: partials sum exactly; 2^-16 cancels in 1/l) ----
#pragma unroll
        for (int a = 0; a < 2; a++) {
            float l = l_run[a];
            l += __shfl_xor(l, 16);
            l += __shfl_xor(l, 32);
            float rl = 1.0f / l;
            size_t row = (size_t)(b * 2048 + q0 + a * 16 + lane15) * 1024 + h * 64 + quad * 4;
#pragma unroll
            for (int c = 0; c < 4; c++) {
                ushort4 pk;
                pk.x = f2b(o[a][c][0] * rl);
                pk.y = f2b(o[a][c][1] * rl);
                pk.z = f2b(o[a][c][2] * rl);
                pk.w = f2b(o[a][c][3] * rl);
                *(ushort4*)&attnout[row + c * 16] = pk;
            }
        }
    }
}

extern "C" void kernel_launch(void* const* d_in, const int* in_sizes, int n_in,
                              void* d_out, int out_size, void* d_ws, size_t ws_size,
                              hipStream_t stream) {
    const float* x    = (const float*)d_in[0];
    const float* wq_w = (const float*)d_in[1];
    const float* wq_b = (const float*)d_in[2];
    const float* wk_w = (const float*)d_in[3];
    const float* wk_b = (const float*)d_in[4];
    const float* wv_w = (const float*)d_in[5];
    const float* wv_b = (const float*)d_in[6];
    const float* wo_w = (const float*)d_in[7];
    const float* wo_b = (const float*)d_in[8];
    float* out = (float*)d_out;

    char* ws = (char*)d_ws;
    size_t off = 0;
    unsigned short* xb      = (unsigned short*)(ws + off); off += (size_t)4096 * 1024 * 2;
    unsigned short* wb      = (unsigned short*)(ws + off); off += (size_t)4 * 1024 * 1024 * 2;
    unsigned short* qbuf    = (unsigned short*)(ws + off); off += (size_t)4096 * 1024 * 2;
    unsigned short* kbuf    = (unsigned short*)(ws + off); off += (size_t)4096 * 1024 * 2;
    unsigned short* vbuf    = (unsigned short*)(ws + off); off += (size_t)4096 * 1024 * 2;
    unsigned short* attnout = (unsigned short*)(ws + off); off += (size_t)4096 * 1024 * 2;
    float* maskbuf          = (float*)(ws + off);          off += 4096 * 4;

    unsigned short* wqb = wb;
    unsigned short* wkb = wb + (1u << 20);
    unsigned short* wvb = wb + (2u << 20);
    unsigned short* wob = wb + (3u << 20);

    cvt_all<<<8192, 256, 0, stream>>>(x, wq_w, wk_w, wv_w, wo_w, xb, wb, maskbuf);

    gemm_qkv<<<dim3(24, 32), 512, 0, stream>>>(xb, wqb, wkb, wvb,
                                               wq_b, wk_b, wv_b, qbuf, kbuf, vbuf);

    attn_kernel<<<512, 512, 0, stream>>>(qbuf, kbuf, vbuf, maskbuf, attnout);

    gemm_proj<<<dim3(16, 64), 256, 0, stream>>>(attnout, wob, wo_b, out);
}

// Round 16
// 180.826 us; speedup vs baseline: 1.9177x; 1.0253x over previous
//
#include <hip/hip_runtime.h>
#include <hip/hip_bf16.h>

typedef short short8 __attribute__((ext_vector_type(8)));
typedef float f32x4 __attribute__((ext_vector_type(4)));

#define MFMA32(a, b, c) __builtin_amdgcn_mfma_f32_16x16x32_bf16(a, b, c, 0, 0, 0)

#if __has_builtin(__builtin_amdgcn_exp2f)
#define EXP2F(x) __builtin_amdgcn_exp2f(x)
#else
#define EXP2F(x) exp2f(x)
#endif

// async global->LDS, 16B per lane; LDS dest = wave-uniform base + lane*16
#define GLL16(gp, lp) __builtin_amdgcn_global_load_lds(                                  \
    (__attribute__((address_space(1))) unsigned int*)(unsigned long long)(const void*)(gp), \
    (__attribute__((address_space(3))) unsigned int*)(lp), 16, 0, 0)

// fp32 -> bf16 RNE
__device__ __forceinline__ unsigned short f2b(float f) {
    union { float f; unsigned int u; } v;
    v.f = f;
    unsigned int u = v.u;
    return (unsigned short)((u + 0x7fffu + ((u >> 16) & 1u)) >> 16);
}

// ---------------- merged cvt: x (+mask) and 4 weights ----------------
// maskbuf carries the softmax fixed-max fold: valid key -> -16.0 (global
// fixed max in log2 domain), pad key -> -1e30. exp2(s + mask) needs no
// per-element subtract and no running max; 2^-16 cancels in normalization.
__global__ void cvt_all(const float* __restrict__ x,
                        const float* __restrict__ w0, const float* __restrict__ w1,
                        const float* __restrict__ w2, const float* __restrict__ w3,
                        unsigned short* __restrict__ xb, unsigned short* __restrict__ wb,
                        float* __restrict__ maskbuf) {
    int blk = blockIdx.x;
    if (blk < 4096) {
        int i = blk * 256 + threadIdx.x;           // 0..1048575 float4s
        float4 v = ((const float4*)x)[i];
        ushort4 o;
        o.x = f2b(v.x); o.y = f2b(v.y); o.z = f2b(v.z); o.w = f2b(v.w);
        ((ushort4*)xb)[i] = o;
        if ((i & 255) == 0)
            maskbuf[i >> 8] = (v.x != 0.0f) ? -16.0f : -1e30f;
    } else {
        int wi = blk - 4096;
        int widx = wi >> 10;
        int i = (wi & 1023) * 256 + threadIdx.x;   // 0..262143 float4s
        const float* src = widx == 0 ? w0 : (widx == 1 ? w1 : (widx == 2 ? w2 : w3));
        float4 v = ((const float4*)src)[i];
        ushort4 o;
        o.x = f2b(v.x); o.y = f2b(v.y); o.z = f2b(v.z); o.w = f2b(v.w);
        ((ushort4*)(wb + ((size_t)widx << 20)))[i] = o;
    }
}

// fold softmax scale (Dh^-0.5) and log2(e) into Q so attn uses raw exp2
#define QSCALE (0.125f * 1.44269504088896341f)

// ---------------- fused QKV GEMM: 512 thr / 8 waves, dbuf, 1 barrier/iter ----------------
// 128x128 tiles, grid (24,32) = 768 blocks = 3/CU (__launch_bounds__(512,6),
// 32 KB LDS). T1 bijective XCD-chunk swizzle: XCD k owns virtual x in
// [3k,3k+3) — its 3 B-panels (768 KB) are L2-resident, A-tiles get 3x
// in-XCD reuse (R13: −2.6 µs with proj). Wave grid 2x4, wave tile 64x32.
__global__ __launch_bounds__(512, 6) void gemm_qkv(
        const unsigned short* __restrict__ A,
        const unsigned short* __restrict__ wq, const unsigned short* __restrict__ wk,
        const unsigned short* __restrict__ wv,
        const float* __restrict__ bq, const float* __restrict__ bk,
        const float* __restrict__ bv,
        unsigned short* __restrict__ qbuf, unsigned short* __restrict__ kbuf,
        unsigned short* __restrict__ vbuf) {
    __shared__ __attribute__((aligned(16))) unsigned short As[2][128 * 32];
    __shared__ __attribute__((aligned(16))) unsigned short Bs[2][128 * 32];
    int tid = threadIdx.x;
    int lane = tid & 63, wave = tid >> 6;            // wave 0..7
    int lane15 = lane & 15, quad = lane >> 4;
    // T1 XCD-chunk swizzle: physical id (x fastest) -> virtual x-major tile
    int orig = blockIdx.x + 24 * blockIdx.y;         // 0..767
    int v = (orig & 7) * 96 + (orig >> 3);           // XCD (orig&7) gets 96 consecutive v
    int xx = v >> 5, yy = v & 31;                    // virtual (x 0..23, y 0..31)
    int seg = xx >> 3;
    int bn = (xx & 7) * 128;
    int bm = yy * 128;
    const unsigned short* Bw = seg == 0 ? wq : (seg == 1 ? wk : wv);
    const float* bias = seg == 0 ? bq : (seg == 1 ? bk : bv);
    int wm = (wave >> 2) * 64, wn = (wave & 3) * 32; // wave tile 64x32

    f32x4 acc[4][2];
#pragma unroll
    for (int i = 0; i < 4; i++)
#pragma unroll
        for (int j = 0; j < 2; j++) acc[i][j] = (f32x4){0.f, 0.f, 0.f, 0.f};

    int arow = tid >> 2, acol = (tid & 3) * 8;       // 512 thr cover 128x32 tile
    const unsigned short* A0 = &A[(size_t)(bm + arow) * 1024 + acol];
    const unsigned short* B0 = &Bw[(size_t)(bn + arow) * 1024 + acol];

    // prologue: stage k-tile 0 into buffer 0 (1 A + 1 B chunk per thread)
    GLL16(A0, &As[0][(size_t)tid * 8]);
    GLL16(B0, &Bs[0][(size_t)tid * 8]);

    for (int it = 0; it < 32; it++) {
        int cur = it & 1;
        __syncthreads();                 // tile[cur] ready; prior reads drained
        if (it < 31) {                   // prefetch tile[cur^1]
            int kn = (it + 1) * 32;
            GLL16(A0 + kn, &As[cur ^ 1][(size_t)tid * 8]);
            GLL16(B0 + kn, &Bs[cur ^ 1][(size_t)tid * 8]);
        }
        const unsigned short* as = As[cur];
        const unsigned short* bs = Bs[cur];
        short8 af[4], bf[2];
#pragma unroll
        for (int i = 0; i < 4; i++)
            af[i] = *(const short8*)&as[(wm + i * 16 + lane15) * 32 + quad * 8];
#pragma unroll
        for (int j = 0; j < 2; j++)
            bf[j] = *(const short8*)&bs[(wn + j * 16 + lane15) * 32 + quad * 8];
#pragma unroll
        for (int i = 0; i < 4; i++)
#pragma unroll
            for (int j = 0; j < 2; j++)
                acc[i][j] = MFMA32(af[i], bf[j], acc[i][j]);
    }

    int bb = bm >> 11;
#pragma unroll
    for (int j = 0; j < 2; j++) {
        int nl = bn + wn + j * 16 + lane15;     // 0..1023
        int h = nl >> 6, d = nl & 63;
        float bv_ = bias[nl];
        if (seg == 2) {
            size_t vbase = ((size_t)((bb * 16 + h) * 64 + d)) * 2048;
#pragma unroll
            for (int i = 0; i < 4; i++) {
                int tk0 = (bm & 2047) + wm + i * 16 + quad * 4;
                int grp = tk0 >> 5;
                ushort4 pk;
                pk.x = f2b(acc[i][j][0] + bv_);
                pk.y = f2b(acc[i][j][1] + bv_);
                pk.z = f2b(acc[i][j][2] + bv_);
                pk.w = f2b(acc[i][j][3] + bv_);
                *(ushort4*)&vbuf[vbase + grp * 32 + quad * 8 + (i & 1) * 4] = pk;
            }
        } else {
#pragma unroll
            for (int i = 0; i < 4; i++)
#pragma unroll
                for (int r = 0; r < 4; r++) {
                    int m = bm + wm + i * 16 + quad * 4 + r;
                    int tk = m & 2047;
                    float v2 = acc[i][j][r] + bv_;
                    size_t off = ((size_t)((bb * 16 + h) * 2048 + tk)) * 64 + d;
                    if (seg == 0) qbuf[off] = f2b(v2 * QSCALE);
                    else          kbuf[off] = f2b(v2);
                }
        }
    }
}

// ---------------- output projection GEMM: 64x64 tiles, BK=64, 4 blocks/CU ----------------
// BK=64: 8 MFMA + 8 ds_read + 4 GLL per wave-iter, 16 iters. LDS 32 KB keeps
// 4 blocks/CU. XOR chunk swizzle on 128B LDS rows (0 conflicts measured).
// T1 bijective XCD-chunk swizzle: XCD k owns virtual bx in [2k,2k+2).
__global__ __launch_bounds__(256, 4) void gemm_proj(
        const unsigned short* __restrict__ A, const unsigned short* __restrict__ Bw,
        const float* __restrict__ bias, float* __restrict__ out) {
    __shared__ __attribute__((aligned(16))) unsigned short As[2][64 * 64];
    __shared__ __attribute__((aligned(16))) unsigned short Bs[2][64 * 64];
    int tid = threadIdx.x;
    int lane = tid & 63, wave = tid >> 6;            // wave 0..3
    int lane15 = lane & 15, quad = lane >> 4;
    int x7 = lane15 & 7;
    // T1 XCD-chunk swizzle: physical (x fastest) -> virtual x-major
    int orig = blockIdx.x + 16 * blockIdx.y;         // 0..1023
    int v = (orig & 7) * 128 + (orig >> 3);
    int bxv = v >> 6, byv = v & 63;                  // virtual (bx 0..15, by 0..63)
    int bn = bxv * 64, bm = byv * 64;
    int wm = (wave >> 1) * 32, wn = (wave & 1) * 32; // wave tile 32x32

    f32x4 acc[2][2];
#pragma unroll
    for (int i = 0; i < 2; i++)
#pragma unroll
        for (int j = 0; j < 2; j++) acc[i][j] = (f32x4){0.f, 0.f, 0.f, 0.f};

    // staging: per iter, A tile 64x64 (512 chunks) + B tile 64x64 (512 chunks);
    // each of 256 threads does 2 A + 2 B GLLs. Chunk ci: row=ci>>3, slot=ci&7
    // holds global k-chunk (ci&7)^(row&7).
#define PSTAGE(buf, kt)                                                                \
    _Pragma("unroll")                                                                  \
    for (int r2 = 0; r2 < 2; r2++) {                                                   \
        int ci = tid + r2 * 256;                                                       \
        int rr = ci >> 3, cc = (ci & 7) ^ (rr & 7);                                    \
        GLL16(&A[(size_t)(bm + rr) * 1024 + (kt) * 64 + cc * 8], &As[buf][(size_t)ci * 8]); \
        GLL16(&Bw[(size_t)(bn + rr) * 1024 + (kt) * 64 + cc * 8], &Bs[buf][(size_t)ci * 8]); \
    }

    PSTAGE(0, 0);

    for (int it = 0; it < 16; it++) {
        int cur = it & 1;
        __syncthreads();
        if (it < 15) PSTAGE(cur ^ 1, it + 1);
        const unsigned short* as = As[cur];
        const unsigned short* bs = Bs[cur];
#pragma unroll
        for (int ksub = 0; ksub < 2; ksub++) {
            short8 af[2], bf[2];
#pragma unroll
            for (int i = 0; i < 2; i++)
                af[i] = *(const short8*)&as[(wm + i * 16 + lane15) * 64 + (((ksub * 4 + quad) ^ x7)) * 8];
#pragma unroll
            for (int j = 0; j < 2; j++)
                bf[j] = *(const short8*)&bs[(wn + j * 16 + lane15) * 64 + (((ksub * 4 + quad) ^ x7)) * 8];
#pragma unroll
            for (int i = 0; i < 2; i++)
#pragma unroll
                for (int j = 0; j < 2; j++)
                    acc[i][j] = MFMA32(af[i], bf[j], acc[i][j]);
        }
    }

#pragma unroll
    for (int j = 0; j < 2; j++) {
        int n = bn + wn + j * 16 + lane15;
        float bv_ = bias[n];
#pragma unroll
        for (int i = 0; i < 2; i++)
#pragma unroll
            for (int r = 0; r < 4; r++) {
                int m = bm + wm + i * 16 + quad * 4 + r;
                out[(size_t)m * 1024 + n] = acc[i][j][r] + bv_;
            }
    }
}

// ---------------- flash attention v12 (R13 state): split-K two-team, fixed-max ----------------
// R16: REVERT of R14/R15's single-buffered-V experiments. R15 proved the
// occupancy theory wrong: grid is 512 blocks = 2/CU, so freeing LDS cannot
// raise residency (no 3rd block exists), and the added barrier cost ~0.7 µs.
// This is the verified best: 512 blocks x 512 thr, 2 teams of 4 waves x 32q
// split-K, KVBLK=64 dbuf (67.5 KB LDS), fixed-max softmax (partials sum
// exactly -> one LDS merge), mask in MFMA C-init, setprio around MFMA.
__global__ __launch_bounds__(512, 4) void attn_kernel(
        const unsigned short* __restrict__ qbuf, const unsigned short* __restrict__ kbuf,
        const unsigned short* __restrict__ vtbuf, const float* __restrict__ maskbuf,
        unsigned short* __restrict__ attnout) {
    // [team][K=0/V=1][dbuf][64 rows * 64 cols] = 64 KB
    __shared__ __attribute__((aligned(16))) unsigned short KVs[2][2][2][64 * 64];
    __shared__ float Lm[4][2][64];

    int id = blockIdx.x;
    int combo = (id & 7) | (((id >> 7) & 3) << 3);   // same (b,h) stays on one XCD
    int qt = (id >> 3) & 15;
    int b = combo >> 4, h = combo & 15;
    int tid = threadIdx.x, lane = tid & 63, wave = tid >> 6;   // wave 0..7
    int team = wave >> 2, wp = wave & 3;
    int lane15 = lane & 15, quad = lane >> 4;
    int q0 = qt * 128 + wp * 32;

    const unsigned short* Q  = qbuf  + (size_t)combo * 2048 * 64;
    const unsigned short* Kp = kbuf  + (size_t)combo * 2048 * 64 + (size_t)team * 1024 * 64;
    const unsigned short* Vt = vtbuf + (size_t)combo * 64 * 2048 + team * 1024;
    const float* mb = maskbuf + b * 2048 + team * 1024;

    // Q as 16x16x32 B-operand: B[n=lane15][k=quad*8+j]; two 16-q tiles, two k-halves
    short8 qf[2][2];
#pragma unroll
    for (int a = 0; a < 2; a++)
#pragma unroll
        for (int g = 0; g < 2; g++)
            qf[a][g] = *(const short8*)&Q[(size_t)(q0 + a * 16 + lane15) * 64 + g * 32 + quad * 8];

    float l_run[2] = {0.f, 0.f};
    f32x4 o[2][4];
#pragma unroll
    for (int a = 0; a < 2; a++)
#pragma unroll
        for (int c = 0; c < 4; c++) o[a][c] = (f32x4){0.f, 0.f, 0.f, 0.f};

    int x7 = lane15 & 7;
    int ci0 = tid & 255;            // per-team chunk id 0..255 (wave-contiguous)

    // staging: per team-iter, K tile 64x64 (512 chunks) + V tile 64x64 (512
    // chunks); each of the 256 team-threads does 2 K + 2 V GLLs.
#define STAGE_KV(buf, kt)                                                              \
    _Pragma("unroll")                                                                  \
    for (int r2 = 0; r2 < 2; r2++) {                                                   \
        int ci = ci0 + r2 * 256;                                                       \
        int rr = ci >> 3, cc = (ci & 7) ^ (rr & 7);                                    \
        GLL16(&Kp[(size_t)((kt) * 64 + rr) * 64 + cc * 8], &KVs[team][0][buf][(size_t)ci * 8]); \
        GLL16(&Vt[(size_t)rr * 2048 + (kt) * 64 + cc * 8], &KVs[team][1][buf][(size_t)ci * 8]); \
    }

    STAGE_KV(0, 0);

    for (int it = 0; it < 16; it++) {
        int cur = it & 1;
        int kb = it * 64;
        __syncthreads();                       // tile[cur] ready; prior reads drained
        if (it < 15) STAGE_KV(cur ^ 1, it + 1);

        const unsigned short* ks = KVs[team][0][cur];
        const unsigned short* vs = KVs[team][1][cur];

        // ---- S^T = K.Q^T : 4 key-tiles x 2 q-tiles, mask in C-init ----
        f32x4 s[2][4];
        __builtin_amdgcn_s_setprio(1);
#pragma unroll
        for (int t = 0; t < 4; t++) {
            f32x4 mkt = *(const f32x4*)&mb[kb + t * 16 + quad * 4];
            int row = t * 16 + lane15;
            short8 k0 = *(const short8*)&ks[row * 64 + (quad ^ x7) * 8];
            short8 k1 = *(const short8*)&ks[row * 64 + ((quad + 4) ^ x7) * 8];
            f32x4 t0 = MFMA32(k0, qf[0][0], mkt);
            s[0][t] = MFMA32(k1, qf[0][1], t0);
            f32x4 t1 = MFMA32(k0, qf[1][0], mkt);
            s[1][t] = MFMA32(k1, qf[1][1], t1);
        }
        __builtin_amdgcn_s_setprio(0);

        // ---- fixed-max softmax: exp2 directly + pack P into MFMA32 B-frags ----
        short8 pb8[2][2];
#pragma unroll
        for (int a = 0; a < 2; a++) {
            float ls = 0.f;
#pragma unroll
            for (int g = 0; g < 2; g++) {
                float e0 = EXP2F(s[a][2 * g][0]);
                float e1 = EXP2F(s[a][2 * g][1]);
                float e2 = EXP2F(s[a][2 * g][2]);
                float e3 = EXP2F(s[a][2 * g][3]);
                float f0 = EXP2F(s[a][2 * g + 1][0]);
                float f1 = EXP2F(s[a][2 * g + 1][1]);
                float f2 = EXP2F(s[a][2 * g + 1][2]);
                float f3 = EXP2F(s[a][2 * g + 1][3]);
                ls += ((e0 + e1) + (e2 + e3)) + ((f0 + f1) + (f2 + f3));
                union { uint4 u; short8 sv; } pu;   // bf16 truncation pack (P >= 0)
                pu.u.x = __builtin_amdgcn_perm(__float_as_uint(e1), __float_as_uint(e0), 0x07060302u);
                pu.u.y = __builtin_amdgcn_perm(__float_as_uint(e3), __float_as_uint(e2), 0x07060302u);
                pu.u.z = __builtin_amdgcn_perm(__float_as_uint(f1), __float_as_uint(f0), 0x07060302u);
                pu.u.w = __builtin_amdgcn_perm(__float_as_uint(f3), __float_as_uint(f2), 0x07060302u);
                pb8[a][g] = pu.sv;
            }
            l_run[a] += ls;
        }

        // ---- O^T += V^T.P^T : MFMA32, A-frag = one b128, shared by both q-tiles ----
        __builtin_amdgcn_s_setprio(1);
#pragma unroll
        for (int c = 0; c < 4; c++) {
            int d = c * 16 + lane15;
#pragma unroll
            for (int g = 0; g < 2; g++) {
                int skc = (g * 4 + quad) ^ x7;
                short8 vv = *(const short8*)&vs[d * 64 + skc * 8];
                o[0][c] = MFMA32(vv, pb8[0][g], o[0][c]);
                o[1][c] = MFMA32(vv, pb8[1][g], o[1][c]);
            }
        }
        __builtin_amdgcn_s_setprio(0);
    }

    // ---- split-K merge: team1 -> LDS (dead staging region), team0 adds ----
    __syncthreads();
    f32x4* omv = (f32x4*)&KVs[0][0][0][0];       // 2048 f32x4 = 32 KB
    if (team == 1) {
#pragma unroll
        for (int a = 0; a < 2; a++) {
#pragma unroll
            for (int c = 0; c < 4; c++)
                omv[(wp * 8 + a * 4 + c) * 64 + lane] = o[a][c];
            Lm[wp][a][lane] = l_run[a];
        }
    }
    __syncthreads();
    if (team == 0) {
#pragma unroll
        for (int a = 0; a < 2; a++) {
            l_run[a] += Lm[wp][a][lane];
#pragma unroll
            for (int c = 0; c < 4; c++)
                o[a][c] += omv[(wp * 8 + a * 4 + c) * 64 + lane];
        }
        // ---- epilogue (fixed-max: partials sum exactly; 2^-16 cancels in 1/l) ----
#pragma unroll
        for (int a = 0; a < 2; a++) {
            float l = l_run[a];
            l += __shfl_xor(l, 16);
            l += __shfl_xor(l, 32);
            float rl = 1.0f / l;
            size_t row = (size_t)(b * 2048 + q0 + a * 16 + lane15) * 1024 + h * 64 + quad * 4;
#pragma unroll
            for (int c = 0; c < 4; c++) {
                ushort4 pk;
                pk.x = f2b(o[a][c][0] * rl);
                pk.y = f2b(o[a][c][1] * rl);
                pk.z = f2b(o[a][c][2] * rl);
                pk.w = f2b(o[a][c][3] * rl);
                *(ushort4*)&attnout[row + c * 16] = pk;
            }
        }
    }
}

extern "C" void kernel_launch(void* const* d_in, const int* in_sizes, int n_in,
                              void* d_out, int out_size, void* d_ws, size_t ws_size,
                              hipStream_t stream) {
    const float* x    = (const float*)d_in[0];
    const float* wq_w = (const float*)d_in[1];
    const float* wq_b = (const float*)d_in[2];
    const float* wk_w = (const float*)d_in[3];
    const float* wk_b = (const float*)d_in[4];
    const float* wv_w = (const float*)d_in[5];
    const float* wv_b = (const float*)d_in[6];
    const float* wo_w = (const float*)d_in[7];
    const float* wo_b = (const float*)d_in[8];
    float* out = (float*)d_out;

    char* ws = (char*)d_ws;
    size_t off = 0;
    unsigned short* xb      = (unsigned short*)(ws + off); off += (size_t)4096 * 1024 * 2;
    unsigned short* wb      = (unsigned short*)(ws + off); off += (size_t)4 * 1024 * 1024 * 2;
    unsigned short* qbuf    = (unsigned short*)(ws + off); off += (size_t)4096 * 1024 * 2;
    unsigned short* kbuf    = (unsigned short*)(ws + off); off += (size_t)4096 * 1024 * 2;
    unsigned short* vbuf    = (unsigned short*)(ws + off); off += (size_t)4096 * 1024 * 2;
    unsigned short* attnout = (unsigned short*)(ws + off); off += (size_t)4096 * 1024 * 2;
    float* maskbuf          = (float*)(ws + off);          off += 4096 * 4;

    unsigned short* wqb = wb;
    unsigned short* wkb = wb + (1u << 20);
    unsigned short* wvb = wb + (2u << 20);
    unsigned short* wob = wb + (3u << 20);

    cvt_all<<<8192, 256, 0, stream>>>(x, wq_w, wk_w, wv_w, wo_w, xb, wb, maskbuf);

    gemm_qkv<<<dim3(24, 32), 512, 0, stream>>>(xb, wqb, wkb, wvb,
                                               wq_b, wk_b, wv_b, qbuf, kbuf, vbuf);

    attn_kernel<<<512, 512, 0, stream>>>(qbuf, kbuf, vbuf, maskbuf, attnout);

    gemm_proj<<<dim3(16, 64), 256, 0, stream>>>(attnout, wob, wo_b, out);
}

// Round 18
// 176.377 us; speedup vs baseline: 1.9661x; 1.0252x over previous
//
#include <hip/hip_runtime.h>
#include <hip/hip_bf16.h>

typedef short short8 __attribute__((ext_vector_type(8)));
typedef float f32x4 __attribute__((ext_vector_type(4)));

#define MFMA32(a, b, c) __builtin_amdgcn_mfma_f32_16x16x32_bf16(a, b, c, 0, 0, 0)

#if __has_builtin(__builtin_amdgcn_exp2f)
#define EXP2F(x) __builtin_amdgcn_exp2f(x)
#else
#define EXP2F(x) exp2f(x)
#endif

// async global->LDS, 16B per lane; LDS dest = wave-uniform base + lane*16
#define GLL16(gp, lp) __builtin_amdgcn_global_load_lds(                                  \
    (__attribute__((address_space(1))) unsigned int*)(unsigned long long)(const void*)(gp), \
    (__attribute__((address_space(3))) unsigned int*)(lp), 16, 0, 0)

// fp32 -> bf16 RNE
__device__ __forceinline__ unsigned short f2b(float f) {
    union { float f; unsigned int u; } v;
    v.f = f;
    unsigned int u = v.u;
    return (unsigned short)((u + 0x7fffu + ((u >> 16) & 1u)) >> 16);
}

// ---------------- merged cvt: x (+mask) and 4 weights ----------------
// maskbuf carries the softmax fixed-max fold: valid key -> -16.0 (global
// fixed max in log2 domain), pad key -> -1e30. exp2(s + mask) needs no
// per-element subtract and no running max; 2^-16 cancels in normalization.
__global__ void cvt_all(const float* __restrict__ x,
                        const float* __restrict__ w0, const float* __restrict__ w1,
                        const float* __restrict__ w2, const float* __restrict__ w3,
                        unsigned short* __restrict__ xb, unsigned short* __restrict__ wb,
                        float* __restrict__ maskbuf) {
    int blk = blockIdx.x;
    if (blk < 4096) {
        int i = blk * 256 + threadIdx.x;           // 0..1048575 float4s
        float4 v = ((const float4*)x)[i];
        ushort4 o;
        o.x = f2b(v.x); o.y = f2b(v.y); o.z = f2b(v.z); o.w = f2b(v.w);
        ((ushort4*)xb)[i] = o;
        if ((i & 255) == 0)
            maskbuf[i >> 8] = (v.x != 0.0f) ? -16.0f : -1e30f;
    } else {
        int wi = blk - 4096;
        int widx = wi >> 10;
        int i = (wi & 1023) * 256 + threadIdx.x;   // 0..262143 float4s
        const float* src = widx == 0 ? w0 : (widx == 1 ? w1 : (widx == 2 ? w2 : w3));
        float4 v = ((const float4*)src)[i];
        ushort4 o;
        o.x = f2b(v.x); o.y = f2b(v.y); o.z = f2b(v.z); o.w = f2b(v.w);
        ((ushort4*)(wb + ((size_t)widx << 20)))[i] = o;
    }
}

// fold softmax scale (Dh^-0.5) and log2(e) into Q so attn uses raw exp2
#define QSCALE (0.125f * 1.44269504088896341f)

// ---------------- fused QKV GEMM: 512 thr / 8 waves, dbuf, 1 barrier/iter ----------------
// 128x128 tiles, grid (24,32) = 768 blocks = 3/CU (__launch_bounds__(512,6),
// 32 KB LDS). T1 bijective XCD-chunk swizzle: XCD k owns virtual x in
// [3k,3k+3) — its 3 B-panels (768 KB) are L2-resident, A-tiles get 3x
// in-XCD reuse (R13: −2.6 µs with proj). Wave grid 2x4, wave tile 64x32.
// R18 (= R17 resubmit after infra failure): s_setprio(1) around the MFMA
// cluster — T5 in the 3-blocks/CU phase-diversity regime (the documented
// GEMM null m190 was lockstep low-residency; attn here measured +1.6%).
__global__ __launch_bounds__(512, 6) void gemm_qkv(
        const unsigned short* __restrict__ A,
        const unsigned short* __restrict__ wq, const unsigned short* __restrict__ wk,
        const unsigned short* __restrict__ wv,
        const float* __restrict__ bq, const float* __restrict__ bk,
        const float* __restrict__ bv,
        unsigned short* __restrict__ qbuf, unsigned short* __restrict__ kbuf,
        unsigned short* __restrict__ vbuf) {
    __shared__ __attribute__((aligned(16))) unsigned short As[2][128 * 32];
    __shared__ __attribute__((aligned(16))) unsigned short Bs[2][128 * 32];
    int tid = threadIdx.x;
    int lane = tid & 63, wave = tid >> 6;            // wave 0..7
    int lane15 = lane & 15, quad = lane >> 4;
    // T1 XCD-chunk swizzle: physical id (x fastest) -> virtual x-major tile
    int orig = blockIdx.x + 24 * blockIdx.y;         // 0..767
    int v = (orig & 7) * 96 + (orig >> 3);           // XCD (orig&7) gets 96 consecutive v
    int xx = v >> 5, yy = v & 31;                    // virtual (x 0..23, y 0..31)
    int seg = xx >> 3;
    int bn = (xx & 7) * 128;
    int bm = yy * 128;
    const unsigned short* Bw = seg == 0 ? wq : (seg == 1 ? wk : wv);
    const float* bias = seg == 0 ? bq : (seg == 1 ? bk : bv);
    int wm = (wave >> 2) * 64, wn = (wave & 3) * 32; // wave tile 64x32

    f32x4 acc[4][2];
#pragma unroll
    for (int i = 0; i < 4; i++)
#pragma unroll
        for (int j = 0; j < 2; j++) acc[i][j] = (f32x4){0.f, 0.f, 0.f, 0.f};

    int arow = tid >> 2, acol = (tid & 3) * 8;       // 512 thr cover 128x32 tile
    const unsigned short* A0 = &A[(size_t)(bm + arow) * 1024 + acol];
    const unsigned short* B0 = &Bw[(size_t)(bn + arow) * 1024 + acol];

    // prologue: stage k-tile 0 into buffer 0 (1 A + 1 B chunk per thread)
    GLL16(A0, &As[0][(size_t)tid * 8]);
    GLL16(B0, &Bs[0][(size_t)tid * 8]);

    for (int it = 0; it < 32; it++) {
        int cur = it & 1;
        __syncthreads();                 // tile[cur] ready; prior reads drained
        if (it < 31) {                   // prefetch tile[cur^1]
            int kn = (it + 1) * 32;
            GLL16(A0 + kn, &As[cur ^ 1][(size_t)tid * 8]);
            GLL16(B0 + kn, &Bs[cur ^ 1][(size_t)tid * 8]);
        }
        const unsigned short* as = As[cur];
        const unsigned short* bs = Bs[cur];
        short8 af[4], bf[2];
#pragma unroll
        for (int i = 0; i < 4; i++)
            af[i] = *(const short8*)&as[(wm + i * 16 + lane15) * 32 + quad * 8];
#pragma unroll
        for (int j = 0; j < 2; j++)
            bf[j] = *(const short8*)&bs[(wn + j * 16 + lane15) * 32 + quad * 8];
        __builtin_amdgcn_s_setprio(1);
#pragma unroll
        for (int i = 0; i < 4; i++)
#pragma unroll
            for (int j = 0; j < 2; j++)
                acc[i][j] = MFMA32(af[i], bf[j], acc[i][j]);
        __builtin_amdgcn_s_setprio(0);
    }

    int bb = bm >> 11;
#pragma unroll
    for (int j = 0; j < 2; j++) {
        int nl = bn + wn + j * 16 + lane15;     // 0..1023
        int h = nl >> 6, d = nl & 63;
        float bv_ = bias[nl];
        if (seg == 2) {
            size_t vbase = ((size_t)((bb * 16 + h) * 64 + d)) * 2048;
#pragma unroll
            for (int i = 0; i < 4; i++) {
                int tk0 = (bm & 2047) + wm + i * 16 + quad * 4;
                int grp = tk0 >> 5;
                ushort4 pk;
                pk.x = f2b(acc[i][j][0] + bv_);
                pk.y = f2b(acc[i][j][1] + bv_);
                pk.z = f2b(acc[i][j][2] + bv_);
                pk.w = f2b(acc[i][j][3] + bv_);
                *(ushort4*)&vbuf[vbase + grp * 32 + quad * 8 + (i & 1) * 4] = pk;
            }
        } else {
#pragma unroll
            for (int i = 0; i < 4; i++)
#pragma unroll
                for (int r = 0; r < 4; r++) {
                    int m = bm + wm + i * 16 + quad * 4 + r;
                    int tk = m & 2047;
                    float v2 = acc[i][j][r] + bv_;
                    size_t off = ((size_t)((bb * 16 + h) * 2048 + tk)) * 64 + d;
                    if (seg == 0) qbuf[off] = f2b(v2 * QSCALE);
                    else          kbuf[off] = f2b(v2);
                }
        }
    }
}

// ---------------- output projection GEMM: 64x64 tiles, BK=64, 4 blocks/CU ----------------
// BK=64: 8 MFMA + 8 ds_read + 4 GLL per wave-iter, 16 iters. LDS 32 KB keeps
// 4 blocks/CU. XOR chunk swizzle on 128B LDS rows (0 conflicts measured).
// T1 bijective XCD-chunk swizzle: XCD k owns virtual bx in [2k,2k+2).
// R18: s_setprio(1) around the MFMA cluster (T5, 4-blocks/CU diversity).
__global__ __launch_bounds__(256, 4) void gemm_proj(
        const unsigned short* __restrict__ A, const unsigned short* __restrict__ Bw,
        const float* __restrict__ bias, float* __restrict__ out) {
    __shared__ __attribute__((aligned(16))) unsigned short As[2][64 * 64];
    __shared__ __attribute__((aligned(16))) unsigned short Bs[2][64 * 64];
    int tid = threadIdx.x;
    int lane = tid & 63, wave = tid >> 6;            // wave 0..3
    int lane15 = lane & 15, quad = lane >> 4;
    int x7 = lane15 & 7;
    // T1 XCD-chunk swizzle: physical (x fastest) -> virtual x-major
    int orig = blockIdx.x + 16 * blockIdx.y;         // 0..1023
    int v = (orig & 7) * 128 + (orig >> 3);
    int bxv = v >> 6, byv = v & 63;                  // virtual (bx 0..15, by 0..63)
    int bn = bxv * 64, bm = byv * 64;
    int wm = (wave >> 1) * 32, wn = (wave & 1) * 32; // wave tile 32x32

    f32x4 acc[2][2];
#pragma unroll
    for (int i = 0; i < 2; i++)
#pragma unroll
        for (int j = 0; j < 2; j++) acc[i][j] = (f32x4){0.f, 0.f, 0.f, 0.f};

    // staging: per iter, A tile 64x64 (512 chunks) + B tile 64x64 (512 chunks);
    // each of 256 threads does 2 A + 2 B GLLs. Chunk ci: row=ci>>3, slot=ci&7
    // holds global k-chunk (ci&7)^(row&7).
#define PSTAGE(buf, kt)                                                                \
    _Pragma("unroll")                                                                  \
    for (int r2 = 0; r2 < 2; r2++) {                                                   \
        int ci = tid + r2 * 256;                                                       \
        int rr = ci >> 3, cc = (ci & 7) ^ (rr & 7);                                    \
        GLL16(&A[(size_t)(bm + rr) * 1024 + (kt) * 64 + cc * 8], &As[buf][(size_t)ci * 8]); \
        GLL16(&Bw[(size_t)(bn + rr) * 1024 + (kt) * 64 + cc * 8], &Bs[buf][(size_t)ci * 8]); \
    }

    PSTAGE(0, 0);

    for (int it = 0; it < 16; it++) {
        int cur = it & 1;
        __syncthreads();
        if (it < 15) PSTAGE(cur ^ 1, it + 1);
        const unsigned short* as = As[cur];
        const unsigned short* bs = Bs[cur];
#pragma unroll
        for (int ksub = 0; ksub < 2; ksub++) {
            short8 af[2], bf[2];
#pragma unroll
            for (int i = 0; i < 2; i++)
                af[i] = *(const short8*)&as[(wm + i * 16 + lane15) * 64 + (((ksub * 4 + quad) ^ x7)) * 8];
#pragma unroll
            for (int j = 0; j < 2; j++)
                bf[j] = *(const short8*)&bs[(wn + j * 16 + lane15) * 64 + (((ksub * 4 + quad) ^ x7)) * 8];
            __builtin_amdgcn_s_setprio(1);
#pragma unroll
            for (int i = 0; i < 2; i++)
#pragma unroll
                for (int j = 0; j < 2; j++)
                    acc[i][j] = MFMA32(af[i], bf[j], acc[i][j]);
            __builtin_amdgcn_s_setprio(0);
        }
    }

#pragma unroll
    for (int j = 0; j < 2; j++) {
        int n = bn + wn + j * 16 + lane15;
        float bv_ = bias[n];
#pragma unroll
        for (int i = 0; i < 2; i++)
#pragma unroll
            for (int r = 0; r < 4; r++) {
                int m = bm + wm + i * 16 + quad * 4 + r;
                out[(size_t)m * 1024 + n] = acc[i][j][r] + bv_;
            }
    }
}

// ---------------- flash attention v12 (R13/R16 state): split-K two-team, fixed-max ----------------
// The verified best: 512 blocks x 512 thr, 2 teams of 4 waves x 32q split-K,
// KVBLK=64 dbuf (67.5 KB LDS), fixed-max softmax (partials sum exactly ->
// one LDS merge), mask in MFMA C-init, setprio around MFMA (+1.6%, R10).
// Occupancy is grid-capped at 2 blocks/CU (R15 measurement); re-slicing
// queries or keys loses LDS reuse 1:1 (R2/R5 invariant) — frozen.
__global__ __launch_bounds__(512, 4) void attn_kernel(
        const unsigned short* __restrict__ qbuf, const unsigned short* __restrict__ kbuf,
        const unsigned short* __restrict__ vtbuf, const float* __restrict__ maskbuf,
        unsigned short* __restrict__ attnout) {
    // [team][K=0/V=1][dbuf][64 rows * 64 cols] = 64 KB
    __shared__ __attribute__((aligned(16))) unsigned short KVs[2][2][2][64 * 64];
    __shared__ float Lm[4][2][64];

    int id = blockIdx.x;
    int combo = (id & 7) | (((id >> 7) & 3) << 3);   // same (b,h) stays on one XCD
    int qt = (id >> 3) & 15;
    int b = combo >> 4, h = combo & 15;
    int tid = threadIdx.x, lane = tid & 63, wave = tid >> 6;   // wave 0..7
    int team = wave >> 2, wp = wave & 3;
    int lane15 = lane & 15, quad = lane >> 4;
    int q0 = qt * 128 + wp * 32;

    const unsigned short* Q  = qbuf  + (size_t)combo * 2048 * 64;
    const unsigned short* Kp = kbuf  + (size_t)combo * 2048 * 64 + (size_t)team * 1024 * 64;
    const unsigned short* Vt = vtbuf + (size_t)combo * 64 * 2048 + team * 1024;
    const float* mb = maskbuf + b * 2048 + team * 1024;

    // Q as 16x16x32 B-operand: B[n=lane15][k=quad*8+j]; two 16-q tiles, two k-halves
    short8 qf[2][2];
#pragma unroll
    for (int a = 0; a < 2; a++)
#pragma unroll
        for (int g = 0; g < 2; g++)
            qf[a][g] = *(const short8*)&Q[(size_t)(q0 + a * 16 + lane15) * 64 + g * 32 + quad * 8];

    float l_run[2] = {0.f, 0.f};
    f32x4 o[2][4];
#pragma unroll
    for (int a = 0; a < 2; a++)
#pragma unroll
        for (int c = 0; c < 4; c++) o[a][c] = (f32x4){0.f, 0.f, 0.f, 0.f};

    int x7 = lane15 & 7;
    int ci0 = tid & 255;            // per-team chunk id 0..255 (wave-contiguous)

    // staging: per team-iter, K tile 64x64 (512 chunks) + V tile 64x64 (512
    // chunks); each of the 256 team-threads does 2 K + 2 V GLLs.
#define STAGE_KV(buf, kt)                                                              \
    _Pragma("unroll")                                                                  \
    for (int r2 = 0; r2 < 2; r2++) {                                                   \
        int ci = ci0 + r2 * 256;                                                       \
        int rr = ci >> 3, cc = (ci & 7) ^ (rr & 7);                                    \
        GLL16(&Kp[(size_t)((kt) * 64 + rr) * 64 + cc * 8], &KVs[team][0][buf][(size_t)ci * 8]); \
        GLL16(&Vt[(size_t)rr * 2048 + (kt) * 64 + cc * 8], &KVs[team][1][buf][(size_t)ci * 8]); \
    }

    STAGE_KV(0, 0);

    for (int it = 0; it < 16; it++) {
        int cur = it & 1;
        int kb = it * 64;
        __syncthreads();                       // tile[cur] ready; prior reads drained
        if (it < 15) STAGE_KV(cur ^ 1, it + 1);

        const unsigned short* ks = KVs[team][0][cur];
        const unsigned short* vs = KVs[team][1][cur];

        // ---- S^T = K.Q^T : 4 key-tiles x 2 q-tiles, mask in C-init ----
        f32x4 s[2][4];
        __builtin_amdgcn_s_setprio(1);
#pragma unroll
        for (int t = 0; t < 4; t++) {
            f32x4 mkt = *(const f32x4*)&mb[kb + t * 16 + quad * 4];
            int row = t * 16 + lane15;
            short8 k0 = *(const short8*)&ks[row * 64 + (quad ^ x7) * 8];
            short8 k1 = *(const short8*)&ks[row * 64 + ((quad + 4) ^ x7) * 8];
            f32x4 t0 = MFMA32(k0, qf[0][0], mkt);
            s[0][t] = MFMA32(k1, qf[0][1], t0);
            f32x4 t1 = MFMA32(k0, qf[1][0], mkt);
            s[1][t] = MFMA32(k1, qf[1][1], t1);
        }
        __builtin_amdgcn_s_setprio(0);

        // ---- fixed-max softmax: exp2 directly + pack P into MFMA32 B-frags ----
        short8 pb8[2][2];
#pragma unroll
        for (int a = 0; a < 2; a++) {
            float ls = 0.f;
#pragma unroll
            for (int g = 0; g < 2; g++) {
                float e0 = EXP2F(s[a][2 * g][0]);
                float e1 = EXP2F(s[a][2 * g][1]);
                float e2 = EXP2F(s[a][2 * g][2]);
                float e3 = EXP2F(s[a][2 * g][3]);
                float f0 = EXP2F(s[a][2 * g + 1][0]);
                float f1 = EXP2F(s[a][2 * g + 1][1]);
                float f2 = EXP2F(s[a][2 * g + 1][2]);
                float f3 = EXP2F(s[a][2 * g + 1][3]);
                ls += ((e0 + e1) + (e2 + e3)) + ((f0 + f1) + (f2 + f3));
                union { uint4 u; short8 sv; } pu;   // bf16 truncation pack (P >= 0)
                pu.u.x = __builtin_amdgcn_perm(__float_as_uint(e1), __float_as_uint(e0), 0x07060302u);
                pu.u.y = __builtin_amdgcn_perm(__float_as_uint(e3), __float_as_uint(e2), 0x07060302u);
                pu.u.z = __builtin_amdgcn_perm(__float_as_uint(f1), __float_as_uint(f0), 0x07060302u);
                pu.u.w = __builtin_amdgcn_perm(__float_as_uint(f3), __float_as_uint(f2), 0x07060302u);
                pb8[a][g] = pu.sv;
            }
            l_run[a] += ls;
        }

        // ---- O^T += V^T.P^T : MFMA32, A-frag = one b128, shared by both q-tiles ----
        __builtin_amdgcn_s_setprio(1);
#pragma unroll
        for (int c = 0; c < 4; c++) {
            int d = c * 16 + lane15;
#pragma unroll
            for (int g = 0; g < 2; g++) {
                int skc = (g * 4 + quad) ^ x7;
                short8 vv = *(const short8*)&vs[d * 64 + skc * 8];
                o[0][c] = MFMA32(vv, pb8[0][g], o[0][c]);
                o[1][c] = MFMA32(vv, pb8[1][g], o[1][c]);
            }
        }
        __builtin_amdgcn_s_setprio(0);
    }

    // ---- split-K merge: team1 -> LDS (dead staging region), team0 adds ----
    __syncthreads();
    f32x4* omv = (f32x4*)&KVs[0][0][0][0];       // 2048 f32x4 = 32 KB
    if (team == 1) {
#pragma unroll
        for (int a = 0; a < 2; a++) {
#pragma unroll
            for (int c = 0; c < 4; c++)
                omv[(wp * 8 + a * 4 + c) * 64 + lane] = o[a][c];
            Lm[wp][a][lane] = l_run[a];
        }
    }
    __syncthreads();
    if (team == 0) {
#pragma unroll
        for (int a = 0; a < 2; a++) {
            l_run[a] += Lm[wp][a][lane];
#pragma unroll
            for (int c = 0; c < 4; c++)
                o[a][c] += omv[(wp * 8 + a * 4 + c) * 64 + lane];
        }
        // ---- epilogue (fixed-max: partials sum exactly; 2^-16 cancels in 1/l) ----
#pragma unroll
        for (int a = 0; a < 2; a++) {
            float l = l_run[a];
            l += __shfl_xor(l, 16);
            l += __shfl_xor(l, 32);
            float rl = 1.0f / l;
            size_t row = (size_t)(b * 2048 + q0 + a * 16 + lane15) * 1024 + h * 64 + quad * 4;
#pragma unroll
            for (int c = 0; c < 4; c++) {
                ushort4 pk;
                pk.x = f2b(o[a][c][0] * rl);
                pk.y = f2b(o[a][c][1] * rl);
                pk.z = f2b(o[a][c][2] * rl);
                pk.w = f2b(o[a][c][3] * rl);
                *(ushort4*)&attnout[row + c * 16] = pk;
            }
        }
    }
}

extern "C" void kernel_launch(void* const* d_in, const int* in_sizes, int n_in,
                              void* d_out, int out_size, void* d_ws, size_t ws_size,
                              hipStream_t stream) {
    const float* x    = (const float*)d_in[0];
    const float* wq_w = (const float*)d_in[1];
    const float* wq_b = (const float*)d_in[2];
    const float* wk_w = (const float*)d_in[3];
    const float* wk_b = (const float*)d_in[4];
    const float* wv_w = (const float*)d_in[5];
    const float* wv_b = (const float*)d_in[6];
    const float* wo_w = (const float*)d_in[7];
    const float* wo_b = (const float*)d_in[8];
    float* out = (float*)d_out;

    char* ws = (char*)d_ws;
    size_t off = 0;
    unsigned short* xb      = (unsigned short*)(ws + off); off += (size_t)4096 * 1024 * 2;
    unsigned short* wb      = (unsigned short*)(ws + off); off += (size_t)4 * 1024 * 1024 * 2;
    unsigned short* qbuf    = (unsigned short*)(ws + off); off += (size_t)4096 * 1024 * 2;
    unsigned short* kbuf    = (unsigned short*)(ws + off); off += (size_t)4096 * 1024 * 2;
    unsigned short* vbuf    = (unsigned short*)(ws + off); off += (size_t)4096 * 1024 * 2;
    unsigned short* attnout = (unsigned short*)(ws + off); off += (size_t)4096 * 1024 * 2;
    float* maskbuf          = (float*)(ws + off);          off += 4096 * 4;

    unsigned short* wqb = wb;
    unsigned short* wkb = wb + (1u << 20);
    unsigned short* wvb = wb + (2u << 20);
    unsigned short* wob = wb + (3u << 20);

    cvt_all<<<8192, 256, 0, stream>>>(x, wq_w, wk_w, wv_w, wo_w, xb, wb, maskbuf);

    gemm_qkv<<<dim3(24, 32), 512, 0, stream>>>(xb, wqb, wkb, wvb,
                                               wq_b, wk_b, wv_b, qbuf, kbuf, vbuf);

    attn_kernel<<<512, 512, 0, stream>>>(qbuf, kbuf, vbuf, maskbuf, attnout);

    gemm_proj<<<dim3(16, 64), 256, 0, stream>>>(attnout, wob, wo_b, out);
}